// Round 22
// baseline (242.464 us; speedup 1.0000x reference)
//
#include <hip/hip_runtime.h>
#include <hip/hip_bf16.h>
#include <hip/hip_fp16.h>
#include <math.h>

#define NEG_SLOPE 0.2f
typedef __hip_bfloat16 bf16;
typedef __attribute__((ext_vector_type(8))) unsigned short ushort8;
typedef _Float16 f16x8 __attribute__((ext_vector_type(8)));
typedef __attribute__((ext_vector_type(8))) short s16x8;
typedef float f32x4 __attribute__((ext_vector_type(4)));

__device__ __forceinline__ float bf2f(unsigned short u) {
    return __uint_as_float(((unsigned)u) << 16);
}
__device__ __forceinline__ unsigned short f2bf_bits(float v) {
    return (unsigned short)(__float_as_uint(__bfloat162float(__float2bfloat16(v))) >> 16);
}

__device__ __forceinline__ void edge_sd(const int* __restrict__ ei, int E, int e, int& s, int& d) {
    if (e < E) { s = ei[e]; d = ei[E + e]; }
    else { s = e - E; d = s; }  // self-loop
}

// ================= CSR build =================
__global__ void k_hist(const int* __restrict__ ei, int E, int Etot, int* __restrict__ deg)
{
    int e = blockIdx.x * blockDim.x + threadIdx.x;
    if (e >= Etot) return;
    int s, d; edge_sd(ei, E, e, s, d);
    atomicAdd(&deg[d], 1);
}

// hierarchical scan
__global__ __launch_bounds__(1024) void k_scan1(
    const int* __restrict__ deg, int* __restrict__ rs, int* __restrict__ bsum, int N)
{
    __shared__ int part[1024];
    int t = threadIdx.x;
    int i = blockIdx.x * 1024 + t;
    int v = (i < N) ? deg[i] : 0;
    part[t] = v;
    __syncthreads();
    for (int off = 1; off < 1024; off <<= 1) {
        int u = (t >= off) ? part[t - off] : 0;
        __syncthreads();
        part[t] += u;
        __syncthreads();
    }
    if (i < N) rs[i] = part[t] - v;
    if (t == 1023) bsum[blockIdx.x] = part[1023];
}

__global__ __launch_bounds__(1024) void k_scan2(
    int* __restrict__ bsum, int* __restrict__ rs, int NB, int N)
{
    __shared__ int part[1024];
    int t = threadIdx.x;
    int v = (t < NB) ? bsum[t] : 0;
    part[t] = v;
    __syncthreads();
    for (int off = 1; off < 1024; off <<= 1) {
        int u = (t >= off) ? part[t - off] : 0;
        __syncthreads();
        part[t] += u;
        __syncthreads();
    }
    if (t < NB) bsum[t] = part[t] - v;
    if (t == 1023) rs[N] = part[1023];
}

__global__ void k_scan3(int* __restrict__ rs, const int* __restrict__ bsum, int N)
{
    int i = blockIdx.x * 256 + threadIdx.x;
    if (i < N) rs[i] += bsum[i >> 10];
}

__global__ void k_fill(const int* __restrict__ ei, int E, int Etot,
                       const int* __restrict__ rs, int* __restrict__ cur,
                       int* __restrict__ csr_src)
{
    int e = blockIdx.x * blockDim.x + threadIdx.x;
    if (e >= Etot) return;
    int s, d; edge_sd(ei, E, e, s, d);
    int pos = rs[d] + atomicAdd(&cur[d], 1);
    csr_src[pos] = s;
}

// ================= merged setup: prew + packw1f + packw2 =================
__global__ __launch_bounds__(512) void k_setup(
    const float* __restrict__ W1, const float* __restrict__ a_src1,
    const float* __restrict__ a_dst1,
    const float* __restrict__ W2, const float* __restrict__ a_src2,
    const float* __restrict__ a_dst2,
    float* __restrict__ wboth, unsigned short* __restrict__ W1f,
    unsigned short* __restrict__ W2f)
{
    int bid = blockIdx.x;
    int t = threadIdx.x;
    if (bid == 0) {
        int k = t >> 3, h = t & 7;
        float s = 0.f, d = 0.f;
        const float* wr = W1 + k * 512 + h * 64;
        const float* as = a_src1 + h * 64;
        const float* ad = a_dst1 + h * 64;
#pragma unroll
        for (int c = 0; c < 64; ++c) { s += wr[c] * as[c]; d += wr[c] * ad[c]; }
        wboth[k * 16 + h] = s;
        wboth[k * 16 + 8 + h] = d;
    } else if (bid <= 64) {
        int i = (bid - 1) * 512 + t;
        int tile = i >> 9;
        int rem = i & 511;
        int l = rem >> 3, j = rem & 7;
        int h = tile >> 3, ks = (tile >> 2) & 1, nt = tile & 3;
        int k = ks * 32 + (l >> 4) * 8 + j;
        int col = h * 64 + nt * 16 + (l & 15);
        W1f[i] = __half_as_ushort(__float2half(W1[k * 512 + col]));
    } else {
        int i = (bid - 65) * 512 + t;
        int tile = i >> 9;
        int rem = i & 511;
        int l = rem >> 3, j = rem & 7;
        int ks = tile >> 1, nt = tile & 1;
        int k = ks * 32 + (l >> 4) * 8 + j;
        int col = nt * 16 + (l & 15);
        float v = 0.f;
        if (col < 17) v = W2[k * 17 + col];
        else if (col == 17) { for (int c = 0; c < 17; ++c) v += W2[k * 17 + c] * a_src2[c]; }
        else if (col == 18) { for (int c = 0; c < 17; ++c) v += W2[k * 17 + c] * a_dst2[c]; }
        W2f[i] = f2bf_bits(v);
    }
}

// per-node attention terms: 256 thr = 4 waves x 4 nodes x 16 lanes
__global__ __launch_bounds__(256) void k_alpha1n(
    const float* __restrict__ x, const float* __restrict__ wboth,
    float* __restrict__ asrc, float* __restrict__ adst, int N)
{
    __shared__ float wl[16][64];   // transposed: wl[c][k]
    int t = threadIdx.x;
    for (int i = t; i < 1024; i += 256) {
        int k = i >> 4, c = i & 15;
        wl[c][k] = wboth[i];
    }
    __syncthreads();
    int wave = t >> 6, lane = t & 63;
    int nsub = lane >> 4, ksub = lane & 15;
    int n = blockIdx.x * 16 + wave * 4 + nsub;
    bool valid = (n < N);
    float xv[4];
#pragma unroll
    for (int i = 0; i < 4; ++i)
        xv[i] = valid ? x[(size_t)n * 64 + i * 16 + ksub] : 0.f;
    float acc[16];
#pragma unroll
    for (int c = 0; c < 16; ++c) acc[c] = 0.f;
#pragma unroll
    for (int i = 0; i < 4; ++i) {
        float xi = xv[i];
        int k = i * 16 + ksub;
#pragma unroll
        for (int c = 0; c < 16; ++c) acc[c] += xi * wl[c][k];
    }
#pragma unroll
    for (int c = 0; c < 16; ++c) {
        acc[c] += __shfl_xor(acc[c], 1, 16);
        acc[c] += __shfl_xor(acc[c], 2, 16);
        acc[c] += __shfl_xor(acc[c], 4, 16);
        acc[c] += __shfl_xor(acc[c], 8, 16);
    }
    if (valid) {
        if (ksub < 8) asrc[n * 8 + ksub] = acc[ksub];
        else          adst[n * 8 + (ksub - 8)] = acc[ksub];
    }
}

// softmax layer1 (R18-proven): bf16 el store, then normalized bf16 alpha
__global__ __launch_bounds__(256) void k_sm1(
    const int* __restrict__ rs, const int* __restrict__ csr_src,
    const float* __restrict__ asrc, const float* __restrict__ adst,
    unsigned short* __restrict__ aEb, int N)
{
    int node = blockIdx.x * 4 + (threadIdx.x >> 6);
    if (node >= N) return;
    int lane = threadIdx.x & 63;
    int h = lane & 7, j0 = lane >> 3;
    int base = rs[node], deg = rs[node + 1] - base;
    float ad = adst[node * 8 + h];
    float m = -1e30f, s = 0.f;
    for (int j = j0; j < deg; j += 8) {
        int src = csr_src[base + j];
        float el = asrc[src * 8 + h] + ad;
        el = el >= 0.f ? el : NEG_SLOPE * el;
        aEb[(size_t)(base + j) * 8 + h] = f2bf_bits(el);
        if (el > m) { s = s * __expf(m - el) + 1.f; m = el; }
        else        { s += __expf(el - m); }
    }
#pragma unroll
    for (int off = 8; off < 64; off <<= 1) {
        float m2 = __shfl_xor(m, off, 64);
        float s2 = __shfl_xor(s, off, 64);
        float M = fmaxf(m, m2);
        s = s * __expf(m - M) + s2 * __expf(m2 - M);
        m = M;
    }
    float inv = 1.f / (s + 1e-16f);
    for (int j = j0; j < deg; j += 8) {
        float el = bf2f(aEb[(size_t)(base + j) * 8 + h]);
        aEb[(size_t)(base + j) * 8 + h] = f2bf_bits(__expf(el - m) * inv);
    }
}

// 8 bf16 alphas (one uint4) FMA'd against one x value
__device__ __forceinline__ void fma8(const uint4& A, float xv, float acc[8])
{
    acc[0] += __uint_as_float(A.x << 16) * xv;
    acc[1] += __uint_as_float(A.x & 0xffff0000u) * xv;
    acc[2] += __uint_as_float(A.y << 16) * xv;
    acc[3] += __uint_as_float(A.y & 0xffff0000u) * xv;
    acc[4] += __uint_as_float(A.z << 16) * xv;
    acc[5] += __uint_as_float(A.z & 0xffff0000u) * xv;
    acc[6] += __uint_as_float(A.w << 16) * xv;
    acc[7] += __uint_as_float(A.w & 0xffff0000u) * xv;
}

// ===== fused: x-space aggregate (f32 x) + MFMA per-head GEMM + bias + ELU =====
// phase 1: 8 edges in flight (R21 was 4; VALU 50%/occ 65% -> latency headroom).
//   Tripwires: VGPR <= 64 (m69 cliff), WRITE ~52 MB, occ >= 60%.
// phase 2: R15-proven MFMA.
#define NPB 16
__global__ __launch_bounds__(512) void k_agg_gemm1(
    const int* __restrict__ rs, const int* __restrict__ csr_src,
    const unsigned short* __restrict__ aEb, const float* __restrict__ x,
    const unsigned short* __restrict__ W1f, const float* __restrict__ b1,
    bf16* __restrict__ y, int N)
{
    __shared__ __align__(16) unsigned short zsh[16 * 512];   // 16 KB f16, swizzled
    int t = threadIdx.x;
    int wave = t >> 6, lane = t & 63;
    int n0 = blockIdx.x * NPB;

    // ---- phase 1: gather 2 nodes per wave, 8 edges in flight ----
#pragma unroll 1
    for (int half = 0; half < 2; ++half) {
        int r = wave + half * 8;
        int n = n0 + r;
        float acc[8];
#pragma unroll
        for (int h = 0; h < 8; ++h) acc[h] = 0.f;
        if (n < N) {
            int base = rs[n], deg = rs[n + 1] - base;
            int j = 0;
            for (; j + 7 < deg; j += 8) {
                int s0 = csr_src[base + j];
                int s1 = csr_src[base + j + 1];
                int s2 = csr_src[base + j + 2];
                int s3 = csr_src[base + j + 3];
                int s4 = csr_src[base + j + 4];
                int s5 = csr_src[base + j + 5];
                int s6 = csr_src[base + j + 6];
                int s7 = csr_src[base + j + 7];
                uint4 A0 = *(const uint4*)(aEb + (size_t)(base + j) * 8);
                uint4 A1 = *(const uint4*)(aEb + (size_t)(base + j + 1) * 8);
                uint4 A2 = *(const uint4*)(aEb + (size_t)(base + j + 2) * 8);
                uint4 A3 = *(const uint4*)(aEb + (size_t)(base + j + 3) * 8);
                float x0 = x[(size_t)s0 * 64 + lane];
                float x1 = x[(size_t)s1 * 64 + lane];
                float x2 = x[(size_t)s2 * 64 + lane];
                float x3 = x[(size_t)s3 * 64 + lane];
                uint4 A4 = *(const uint4*)(aEb + (size_t)(base + j + 4) * 8);
                uint4 A5 = *(const uint4*)(aEb + (size_t)(base + j + 5) * 8);
                uint4 A6 = *(const uint4*)(aEb + (size_t)(base + j + 6) * 8);
                uint4 A7 = *(const uint4*)(aEb + (size_t)(base + j + 7) * 8);
                float x4 = x[(size_t)s4 * 64 + lane];
                float x5 = x[(size_t)s5 * 64 + lane];
                float x6 = x[(size_t)s6 * 64 + lane];
                float x7 = x[(size_t)s7 * 64 + lane];
                fma8(A0, x0, acc); fma8(A1, x1, acc);
                fma8(A2, x2, acc); fma8(A3, x3, acc);
                fma8(A4, x4, acc); fma8(A5, x5, acc);
                fma8(A6, x6, acc); fma8(A7, x7, acc);
            }
            for (; j + 3 < deg; j += 4) {
                int s0 = csr_src[base + j];
                int s1 = csr_src[base + j + 1];
                int s2 = csr_src[base + j + 2];
                int s3 = csr_src[base + j + 3];
                uint4 A0 = *(const uint4*)(aEb + (size_t)(base + j) * 8);
                uint4 A1 = *(const uint4*)(aEb + (size_t)(base + j + 1) * 8);
                uint4 A2 = *(const uint4*)(aEb + (size_t)(base + j + 2) * 8);
                uint4 A3 = *(const uint4*)(aEb + (size_t)(base + j + 3) * 8);
                float x0 = x[(size_t)s0 * 64 + lane];
                float x1 = x[(size_t)s1 * 64 + lane];
                float x2 = x[(size_t)s2 * 64 + lane];
                float x3 = x[(size_t)s3 * 64 + lane];
                fma8(A0, x0, acc); fma8(A1, x1, acc);
                fma8(A2, x2, acc); fma8(A3, x3, acc);
            }
            for (; j < deg; ++j) {
                int s0 = csr_src[base + j];
                uint4 A0 = *(const uint4*)(aEb + (size_t)(base + j) * 8);
                float x0 = x[(size_t)s0 * 64 + lane];
                fma8(A0, x0, acc);
            }
        }
        unsigned xr = (unsigned)((r & 7) << 4);
#pragma unroll
        for (int h = 0; h < 8; ++h) {
            unsigned byte = ((unsigned)(r * 1024 + h * 128 + lane * 2)) ^ xr;
            *(unsigned short*)((char*)zsh + byte) =
                __half_as_ushort(__float2half(acc[h]));
        }
    }
    __syncthreads();

    // ---- phase 2: y[n0+row][h*64+nt*16+col] via MFMA (R15-proven) ----
    {
        int h = wave;
        int rA = lane & 15, q = lane >> 4;
        f32x4 acc[4] = {{0.f,0.f,0.f,0.f},{0.f,0.f,0.f,0.f},
                        {0.f,0.f,0.f,0.f},{0.f,0.f,0.f,0.f}};
        const uint4* W1f4 = (const uint4*)W1f;
#pragma unroll
        for (int ks = 0; ks < 2; ++ks) {
            unsigned byte = ((unsigned)(rA * 1024 + h * 128 + ks * 64 + q * 16))
                            ^ ((unsigned)((rA & 7) << 4));
            uint4 au = *(const uint4*)((const char*)zsh + byte);
            f16x8 a = __builtin_bit_cast(f16x8, au);
#pragma unroll
            for (int nt = 0; nt < 4; ++nt) {
                int tile = ((h * 2 + ks) << 2) | nt;
                f16x8 b = __builtin_bit_cast(f16x8, W1f4[tile * 64 + lane]);
                acc[nt] = __builtin_amdgcn_mfma_f32_16x16x32_f16(a, b, acc[nt], 0, 0, 0);
            }
        }
        int cl = lane & 15, qr = lane >> 4;
#pragma unroll
        for (int nt = 0; nt < 4; ++nt) {
            int colo = h * 64 + nt * 16 + cl;
            float bias = b1[colo];
#pragma unroll
            for (int j = 0; j < 4; ++j) {
                int row = qr * 4 + j;
                int nn = n0 + row;
                if (nn < N) {
                    float v = acc[nt][j] + bias;
                    v = v > 0.f ? v : __expf(v) - 1.f;
                    y[(size_t)nn * 512 + colo] = __float2bfloat16(v);
                }
            }
        }
    }
}

// ================= Layer 2: MFMA gemm2, no LDS (R16-proven) =================
__global__ __launch_bounds__(512) void k_gemm2(
    const bf16* __restrict__ y, const unsigned short* __restrict__ W2f,
    float* __restrict__ h2, float* __restrict__ asrc, float* __restrict__ adst, int N)
{
    int t = threadIdx.x;
    int wave = t >> 6, lane = t & 63;
    int n0 = blockIdx.x * 128 + wave * 16;
    int rA = lane & 15, q = lane >> 4;
    f32x4 acc0 = {0.f,0.f,0.f,0.f}, acc1 = {0.f,0.f,0.f,0.f};
    const uint4* W2f4 = (const uint4*)W2f;
    const bf16* yrow = y + (size_t)(n0 + rA) * 512;
#pragma unroll 1
    for (int ks = 0; ks < 16; ++ks) {
        uint4 au = *(const uint4*)(yrow + ks * 32 + q * 8);
        s16x8 a = __builtin_bit_cast(s16x8, au);
        s16x8 b0 = __builtin_bit_cast(s16x8, W2f4[(ks * 2 + 0) * 64 + lane]);
        s16x8 b1 = __builtin_bit_cast(s16x8, W2f4[(ks * 2 + 1) * 64 + lane]);
        acc0 = __builtin_amdgcn_mfma_f32_16x16x32_bf16(a, b0, acc0, 0, 0, 0);
        acc1 = __builtin_amdgcn_mfma_f32_16x16x32_bf16(a, b1, acc1, 0, 0, 0);
    }
    int cl = lane & 15, qr = lane >> 4;
#pragma unroll
    for (int j = 0; j < 4; ++j) {
        int n = n0 + qr * 4 + j;
        if (n < N) {
            h2[(size_t)n * 17 + cl] = acc0[j];
            if (cl == 0) h2[(size_t)n * 17 + 16] = acc1[j];
            if (cl == 1) asrc[n] = acc1[j];
            if (cl == 2) adst[n] = acc1[j];
        }
    }
}

// ===== fused layer2 softmax + aggregate + bias + log_softmax =====
// pass B: 4 edges in flight
__global__ __launch_bounds__(256) void k_out(
    const int* __restrict__ rs, const int* __restrict__ csr_src,
    const float* __restrict__ asrc, const float* __restrict__ adst,
    const float* __restrict__ h2,
    const float* __restrict__ b2, float* __restrict__ out, int N)
{
    int node = blockIdx.x * 4 + (threadIdx.x >> 6);
    if (node >= N) return;
    int lane = threadIdx.x & 63;
    int base = rs[node], deg = rs[node + 1] - base;
    float ad = adst[node];

    float m = -1e30f, s = 0.f;
    for (int j = lane; j < deg; j += 64) {
        float el = asrc[csr_src[base + j]] + ad;
        el = el >= 0.f ? el : NEG_SLOPE * el;
        if (el > m) { s = s * __expf(m - el) + 1.f; m = el; }
        else        { s += __expf(el - m); }
    }
#pragma unroll
    for (int off = 1; off < 64; off <<= 1) {
        float m2 = __shfl_xor(m, off, 64);
        float s2 = __shfl_xor(s, off, 64);
        float M = fmaxf(m, m2);
        s = s * __expf(m - M) + s2 * __expf(m2 - M);
        m = M;
    }
    float inv = 1.f / (s + 1e-16f);

    int c = lane & 31, jsub = lane >> 5;
    int end = base + deg;
    float acc = 0.f;
    if (c < 17) {
        int p = base + jsub;
        for (; p + 6 < end; p += 8) {
            int src0 = csr_src[p];
            int src1 = csr_src[p + 2];
            int src2 = csr_src[p + 4];
            int src3 = csr_src[p + 6];
            float e0 = asrc[src0] + ad;
            float e1 = asrc[src1] + ad;
            float e2 = asrc[src2] + ad;
            float e3 = asrc[src3] + ad;
            float h0 = h2[(size_t)src0 * 17 + c];
            float h1 = h2[(size_t)src1 * 17 + c];
            float h0b = h2[(size_t)src2 * 17 + c];
            float h1b = h2[(size_t)src3 * 17 + c];
            e0 = e0 >= 0.f ? e0 : NEG_SLOPE * e0;
            e1 = e1 >= 0.f ? e1 : NEG_SLOPE * e1;
            e2 = e2 >= 0.f ? e2 : NEG_SLOPE * e2;
            e3 = e3 >= 0.f ? e3 : NEG_SLOPE * e3;
            acc += __expf(e0 - m) * inv * h0 + __expf(e1 - m) * inv * h1
                 + __expf(e2 - m) * inv * h0b + __expf(e3 - m) * inv * h1b;
        }
        for (; p < end; p += 2) {
            int src = csr_src[p];
            float el = asrc[src] + ad;
            el = el >= 0.f ? el : NEG_SLOPE * el;
            acc += __expf(el - m) * inv * h2[(size_t)src * 17 + c];
        }
    }
    acc += __shfl_xor(acc, 32, 64);
    float logit = (c < 17) ? acc + b2[c] : -1e30f;
    float mm = logit;
#pragma unroll
    for (int off = 1; off < 32; off <<= 1) mm = fmaxf(mm, __shfl_xor(mm, off, 32));
    float p = (c < 17) ? __expf(logit - mm) : 0.f;
    float ssum = p;
#pragma unroll
    for (int off = 1; off < 32; off <<= 1) ssum += __shfl_xor(ssum, off, 32);
    if (c < 17 && jsub == 0) out[(size_t)node * 17 + c] = logit - mm - logf(ssum);
}

extern "C" void kernel_launch(void* const* d_in, const int* in_sizes, int n_in,
                              void* d_out, int out_size, void* d_ws, size_t ws_size,
                              hipStream_t stream)
{
    const float* x      = (const float*)d_in[0];
    const int*   ei     = (const int*)d_in[1];
    const float* W1     = (const float*)d_in[2];
    const float* asrc1w = (const float*)d_in[3];
    const float* adst1w = (const float*)d_in[4];
    const float* b1     = (const float*)d_in[5];
    const float* W2     = (const float*)d_in[6];
    const float* asrc2w = (const float*)d_in[7];
    const float* adst2w = (const float*)d_in[8];
    const float* b2     = (const float*)d_in[9];
    float* out = (float*)d_out;

    const int N = in_sizes[0] / 64;
    const int E = in_sizes[1] / 2;
    const int Etot = N + E;
    const int NB = (N + 1023) / 1024;

    // workspace layout
    float* ws = (float*)d_ws;
    size_t o = 0;
    bf16*  y      = (bf16*)(ws + o); o += (size_t)N * 256;   // N*512 bf16
    float* wboth  = ws + o; o += 1024;
    unsigned short* W1f = (unsigned short*)(ws + o); o += 64 * 512 / 2;  // 32768 halves
    unsigned short* W2f = (unsigned short*)(ws + o); o += 32 * 512 / 2;  // 16384 bf16
    float* asrc1  = ws + o; o += (size_t)N * 8;
    float* adst1  = ws + o; o += (size_t)N * 8;
    unsigned short* aEb = (unsigned short*)(ws + o); o += (size_t)Etot * 4;  // Etot*8 bf16
    float* h2     = ws + o; o += (size_t)N * 17;
    float* asrc2  = ws + o; o += (size_t)N;
    float* adst2  = ws + o; o += (size_t)N;
    int* deg      = (int*)(ws + o); o += (size_t)N;
    int* cur      = (int*)(ws + o); o += (size_t)N;
    int* rs       = (int*)(ws + o); o += (size_t)N + 1;
    int* bsum     = (int*)(ws + o); o += 1024;
    int* csr_src  = (int*)(ws + o); o += (size_t)Etot;

    // deg and cur are adjacent: one memset covers both
    hipMemsetAsync(deg, 0, (size_t)N * 2 * 4, stream);

    // CSR build (hierarchical scan)
    {
        int blk = 256, g = (Etot + blk - 1) / blk;
        k_hist<<<g, blk, 0, stream>>>(ei, E, Etot, deg);
        k_scan1<<<NB, 1024, 0, stream>>>(deg, rs, bsum, N);
        k_scan2<<<1, 1024, 0, stream>>>(bsum, rs, NB, N);
        k_scan3<<<(N + 255) / 256, 256, 0, stream>>>(rs, bsum, N);
        k_fill<<<g, blk, 0, stream>>>(ei, E, Etot, rs, cur, csr_src);
    }

    // merged setup (wboth + W1f + W2f)
    k_setup<<<97, 512, 0, stream>>>(W1, asrc1w, adst1w, W2, asrc2w, adst2w,
                                    wboth, W1f, W2f);

    // layer 1
    k_alpha1n<<<(N + 15) / 16, 256, 0, stream>>>(x, wboth, asrc1, adst1, N);
    k_sm1<<<(N + 3) / 4, 256, 0, stream>>>(rs, csr_src, asrc1, adst1, aEb, N);
    k_agg_gemm1<<<(N + NPB - 1) / NPB, 512, 0, stream>>>(
        rs, csr_src, aEb, x, W1f, b1, y, N);

    // layer 2
    k_gemm2<<<(N + 127) / 128, 512, 0, stream>>>(y, W2f, h2, asrc2, adst2, N);
    k_out<<<(N + 3) / 4, 256, 0, stream>>>(rs, csr_src, asrc2, adst2, h2, b2, out, N);
}

// Round 23
// 218.616 us; speedup vs baseline: 1.1091x; 1.1091x over previous
//
#include <hip/hip_runtime.h>
#include <hip/hip_bf16.h>
#include <hip/hip_fp16.h>
#include <math.h>

#define NEG_SLOPE 0.2f
typedef __hip_bfloat16 bf16;
typedef __attribute__((ext_vector_type(8))) unsigned short ushort8;
typedef _Float16 f16x8 __attribute__((ext_vector_type(8)));
typedef __attribute__((ext_vector_type(8))) short s16x8;
typedef float f32x4 __attribute__((ext_vector_type(4)));

__device__ __forceinline__ float bf2f(unsigned short u) {
    return __uint_as_float(((unsigned)u) << 16);
}
__device__ __forceinline__ unsigned short f2bf_bits(float v) {
    return (unsigned short)(__float_as_uint(__bfloat162float(__float2bfloat16(v))) >> 16);
}

__device__ __forceinline__ void edge_sd(const int* __restrict__ ei, int E, int e, int& s, int& d) {
    if (e < E) { s = ei[e]; d = ei[E + e]; }
    else { s = e - E; d = s; }  // self-loop
}

// ================= CSR build =================
__global__ void k_hist(const int* __restrict__ ei, int E, int Etot, int* __restrict__ deg)
{
    int e = blockIdx.x * blockDim.x + threadIdx.x;
    if (e >= Etot) return;
    int s, d; edge_sd(ei, E, e, s, d);
    atomicAdd(&deg[d], 1);
}

// hierarchical scan
__global__ __launch_bounds__(1024) void k_scan1(
    const int* __restrict__ deg, int* __restrict__ rs, int* __restrict__ bsum, int N)
{
    __shared__ int part[1024];
    int t = threadIdx.x;
    int i = blockIdx.x * 1024 + t;
    int v = (i < N) ? deg[i] : 0;
    part[t] = v;
    __syncthreads();
    for (int off = 1; off < 1024; off <<= 1) {
        int u = (t >= off) ? part[t - off] : 0;
        __syncthreads();
        part[t] += u;
        __syncthreads();
    }
    if (i < N) rs[i] = part[t] - v;
    if (t == 1023) bsum[blockIdx.x] = part[1023];
}

__global__ __launch_bounds__(1024) void k_scan2(
    int* __restrict__ bsum, int* __restrict__ rs, int NB, int N)
{
    __shared__ int part[1024];
    int t = threadIdx.x;
    int v = (t < NB) ? bsum[t] : 0;
    part[t] = v;
    __syncthreads();
    for (int off = 1; off < 1024; off <<= 1) {
        int u = (t >= off) ? part[t - off] : 0;
        __syncthreads();
        part[t] += u;
        __syncthreads();
    }
    if (t < NB) bsum[t] = part[t] - v;
    if (t == 1023) rs[N] = part[1023];
}

__global__ void k_scan3(int* __restrict__ rs, const int* __restrict__ bsum, int N)
{
    int i = blockIdx.x * 256 + threadIdx.x;
    if (i < N) rs[i] += bsum[i >> 10];
}

__global__ void k_fill(const int* __restrict__ ei, int E, int Etot,
                       const int* __restrict__ rs, int* __restrict__ cur,
                       int* __restrict__ csr_src)
{
    int e = blockIdx.x * blockDim.x + threadIdx.x;
    if (e >= Etot) return;
    int s, d; edge_sd(ei, E, e, s, d);
    int pos = rs[d] + atomicAdd(&cur[d], 1);
    csr_src[pos] = s;
}

// ================= merged setup: prew + packw1f + packw2 =================
__global__ __launch_bounds__(512) void k_setup(
    const float* __restrict__ W1, const float* __restrict__ a_src1,
    const float* __restrict__ a_dst1,
    const float* __restrict__ W2, const float* __restrict__ a_src2,
    const float* __restrict__ a_dst2,
    float* __restrict__ wboth, unsigned short* __restrict__ W1f,
    unsigned short* __restrict__ W2f)
{
    int bid = blockIdx.x;
    int t = threadIdx.x;
    if (bid == 0) {
        int k = t >> 3, h = t & 7;
        float s = 0.f, d = 0.f;
        const float* wr = W1 + k * 512 + h * 64;
        const float* as = a_src1 + h * 64;
        const float* ad = a_dst1 + h * 64;
#pragma unroll
        for (int c = 0; c < 64; ++c) { s += wr[c] * as[c]; d += wr[c] * ad[c]; }
        wboth[k * 16 + h] = s;
        wboth[k * 16 + 8 + h] = d;
    } else if (bid <= 64) {
        int i = (bid - 1) * 512 + t;
        int tile = i >> 9;
        int rem = i & 511;
        int l = rem >> 3, j = rem & 7;
        int h = tile >> 3, ks = (tile >> 2) & 1, nt = tile & 3;
        int k = ks * 32 + (l >> 4) * 8 + j;
        int col = h * 64 + nt * 16 + (l & 15);
        W1f[i] = __half_as_ushort(__float2half(W1[k * 512 + col]));
    } else {
        int i = (bid - 65) * 512 + t;
        int tile = i >> 9;
        int rem = i & 511;
        int l = rem >> 3, j = rem & 7;
        int ks = tile >> 1, nt = tile & 1;
        int k = ks * 32 + (l >> 4) * 8 + j;
        int col = nt * 16 + (l & 15);
        float v = 0.f;
        if (col < 17) v = W2[k * 17 + col];
        else if (col == 17) { for (int c = 0; c < 17; ++c) v += W2[k * 17 + c] * a_src2[c]; }
        else if (col == 18) { for (int c = 0; c < 17; ++c) v += W2[k * 17 + c] * a_dst2[c]; }
        W2f[i] = f2bf_bits(v);
    }
}

// per-node attention terms: 256 thr = 4 waves x 4 nodes x 16 lanes
__global__ __launch_bounds__(256) void k_alpha1n(
    const float* __restrict__ x, const float* __restrict__ wboth,
    float* __restrict__ asrc, float* __restrict__ adst, int N)
{
    __shared__ float wl[16][64];   // transposed: wl[c][k]
    int t = threadIdx.x;
    for (int i = t; i < 1024; i += 256) {
        int k = i >> 4, c = i & 15;
        wl[c][k] = wboth[i];
    }
    __syncthreads();
    int wave = t >> 6, lane = t & 63;
    int nsub = lane >> 4, ksub = lane & 15;
    int n = blockIdx.x * 16 + wave * 4 + nsub;
    bool valid = (n < N);
    float xv[4];
#pragma unroll
    for (int i = 0; i < 4; ++i)
        xv[i] = valid ? x[(size_t)n * 64 + i * 16 + ksub] : 0.f;
    float acc[16];
#pragma unroll
    for (int c = 0; c < 16; ++c) acc[c] = 0.f;
#pragma unroll
    for (int i = 0; i < 4; ++i) {
        float xi = xv[i];
        int k = i * 16 + ksub;
#pragma unroll
        for (int c = 0; c < 16; ++c) acc[c] += xi * wl[c][k];
    }
#pragma unroll
    for (int c = 0; c < 16; ++c) {
        acc[c] += __shfl_xor(acc[c], 1, 16);
        acc[c] += __shfl_xor(acc[c], 2, 16);
        acc[c] += __shfl_xor(acc[c], 4, 16);
        acc[c] += __shfl_xor(acc[c], 8, 16);
    }
    if (valid) {
        if (ksub < 8) asrc[n * 8 + ksub] = acc[ksub];
        else          adst[n * 8 + (ksub - 8)] = acc[ksub];
    }
}

// softmax layer1 (R18-proven): bf16 el store, then normalized bf16 alpha
__global__ __launch_bounds__(256) void k_sm1(
    const int* __restrict__ rs, const int* __restrict__ csr_src,
    const float* __restrict__ asrc, const float* __restrict__ adst,
    unsigned short* __restrict__ aEb, int N)
{
    int node = blockIdx.x * 4 + (threadIdx.x >> 6);
    if (node >= N) return;
    int lane = threadIdx.x & 63;
    int h = lane & 7, j0 = lane >> 3;
    int base = rs[node], deg = rs[node + 1] - base;
    float ad = adst[node * 8 + h];
    float m = -1e30f, s = 0.f;
    for (int j = j0; j < deg; j += 8) {
        int src = csr_src[base + j];
        float el = asrc[src * 8 + h] + ad;
        el = el >= 0.f ? el : NEG_SLOPE * el;
        aEb[(size_t)(base + j) * 8 + h] = f2bf_bits(el);
        if (el > m) { s = s * __expf(m - el) + 1.f; m = el; }
        else        { s += __expf(el - m); }
    }
#pragma unroll
    for (int off = 8; off < 64; off <<= 1) {
        float m2 = __shfl_xor(m, off, 64);
        float s2 = __shfl_xor(s, off, 64);
        float M = fmaxf(m, m2);
        s = s * __expf(m - M) + s2 * __expf(m2 - M);
        m = M;
    }
    float inv = 1.f / (s + 1e-16f);
    for (int j = j0; j < deg; j += 8) {
        float el = bf2f(aEb[(size_t)(base + j) * 8 + h]);
        aEb[(size_t)(base + j) * 8 + h] = f2bf_bits(__expf(el - m) * inv);
    }
}

// 8 bf16 alphas (one uint4) FMA'd against one x value
__device__ __forceinline__ void fma8(const uint4& A, float xv, float acc[8])
{
    acc[0] += __uint_as_float(A.x << 16) * xv;
    acc[1] += __uint_as_float(A.x & 0xffff0000u) * xv;
    acc[2] += __uint_as_float(A.y << 16) * xv;
    acc[3] += __uint_as_float(A.y & 0xffff0000u) * xv;
    acc[4] += __uint_as_float(A.z << 16) * xv;
    acc[5] += __uint_as_float(A.z & 0xffff0000u) * xv;
    acc[6] += __uint_as_float(A.w << 16) * xv;
    acc[7] += __uint_as_float(A.w & 0xffff0000u) * xv;
}

// ===== fused: x-space aggregate (f32 x) + MFMA per-head GEMM + bias + ELU =====
// phase 1: 4 edges in flight @ 32 VGPR — MEASURED OPTIMUM. Do not change depth:
//   2-edge (R16) ~80 us; 8-edge (R22) 85 us @ 48 VGPR/37% occ. TLP > per-wave ILP.
// phase 2: R15-proven MFMA.
#define NPB 16
__global__ __launch_bounds__(512) void k_agg_gemm1(
    const int* __restrict__ rs, const int* __restrict__ csr_src,
    const unsigned short* __restrict__ aEb, const float* __restrict__ x,
    const unsigned short* __restrict__ W1f, const float* __restrict__ b1,
    bf16* __restrict__ y, int N)
{
    __shared__ __align__(16) unsigned short zsh[16 * 512];   // 16 KB f16, swizzled
    int t = threadIdx.x;
    int wave = t >> 6, lane = t & 63;
    int n0 = blockIdx.x * NPB;

    // ---- phase 1: gather 2 nodes per wave, 4 edges in flight ----
#pragma unroll 1
    for (int half = 0; half < 2; ++half) {
        int r = wave + half * 8;
        int n = n0 + r;
        float acc[8];
#pragma unroll
        for (int h = 0; h < 8; ++h) acc[h] = 0.f;
        if (n < N) {
            int base = rs[n], deg = rs[n + 1] - base;
            int j = 0;
            for (; j + 3 < deg; j += 4) {
                int s0 = csr_src[base + j];
                int s1 = csr_src[base + j + 1];
                int s2 = csr_src[base + j + 2];
                int s3 = csr_src[base + j + 3];
                uint4 A0 = *(const uint4*)(aEb + (size_t)(base + j) * 8);
                uint4 A1 = *(const uint4*)(aEb + (size_t)(base + j + 1) * 8);
                uint4 A2 = *(const uint4*)(aEb + (size_t)(base + j + 2) * 8);
                uint4 A3 = *(const uint4*)(aEb + (size_t)(base + j + 3) * 8);
                float x0 = x[(size_t)s0 * 64 + lane];
                float x1 = x[(size_t)s1 * 64 + lane];
                float x2 = x[(size_t)s2 * 64 + lane];
                float x3 = x[(size_t)s3 * 64 + lane];
                fma8(A0, x0, acc);
                fma8(A1, x1, acc);
                fma8(A2, x2, acc);
                fma8(A3, x3, acc);
            }
            for (; j < deg; ++j) {
                int s0 = csr_src[base + j];
                uint4 A0 = *(const uint4*)(aEb + (size_t)(base + j) * 8);
                float x0 = x[(size_t)s0 * 64 + lane];
                fma8(A0, x0, acc);
            }
        }
        unsigned xr = (unsigned)((r & 7) << 4);
#pragma unroll
        for (int h = 0; h < 8; ++h) {
            unsigned byte = ((unsigned)(r * 1024 + h * 128 + lane * 2)) ^ xr;
            *(unsigned short*)((char*)zsh + byte) =
                __half_as_ushort(__float2half(acc[h]));
        }
    }
    __syncthreads();

    // ---- phase 2: y[n0+row][h*64+nt*16+col] via MFMA (R15-proven) ----
    {
        int h = wave;
        int rA = lane & 15, q = lane >> 4;
        f32x4 acc[4] = {{0.f,0.f,0.f,0.f},{0.f,0.f,0.f,0.f},
                        {0.f,0.f,0.f,0.f},{0.f,0.f,0.f,0.f}};
        const uint4* W1f4 = (const uint4*)W1f;
#pragma unroll
        for (int ks = 0; ks < 2; ++ks) {
            unsigned byte = ((unsigned)(rA * 1024 + h * 128 + ks * 64 + q * 16))
                            ^ ((unsigned)((rA & 7) << 4));
            uint4 au = *(const uint4*)((const char*)zsh + byte);
            f16x8 a = __builtin_bit_cast(f16x8, au);
#pragma unroll
            for (int nt = 0; nt < 4; ++nt) {
                int tile = ((h * 2 + ks) << 2) | nt;
                f16x8 b = __builtin_bit_cast(f16x8, W1f4[tile * 64 + lane]);
                acc[nt] = __builtin_amdgcn_mfma_f32_16x16x32_f16(a, b, acc[nt], 0, 0, 0);
            }
        }
        int cl = lane & 15, qr = lane >> 4;
#pragma unroll
        for (int nt = 0; nt < 4; ++nt) {
            int colo = h * 64 + nt * 16 + cl;
            float bias = b1[colo];
#pragma unroll
            for (int j = 0; j < 4; ++j) {
                int row = qr * 4 + j;
                int nn = n0 + row;
                if (nn < N) {
                    float v = acc[nt][j] + bias;
                    v = v > 0.f ? v : __expf(v) - 1.f;
                    y[(size_t)nn * 512 + colo] = __float2bfloat16(v);
                }
            }
        }
    }
}

// ================= Layer 2: MFMA gemm2, no LDS (R16-proven) =================
__global__ __launch_bounds__(512) void k_gemm2(
    const bf16* __restrict__ y, const unsigned short* __restrict__ W2f,
    float* __restrict__ h2, float* __restrict__ asrc, float* __restrict__ adst, int N)
{
    int t = threadIdx.x;
    int wave = t >> 6, lane = t & 63;
    int n0 = blockIdx.x * 128 + wave * 16;
    int rA = lane & 15, q = lane >> 4;
    f32x4 acc0 = {0.f,0.f,0.f,0.f}, acc1 = {0.f,0.f,0.f,0.f};
    const uint4* W2f4 = (const uint4*)W2f;
    const bf16* yrow = y + (size_t)(n0 + rA) * 512;
#pragma unroll 1
    for (int ks = 0; ks < 16; ++ks) {
        uint4 au = *(const uint4*)(yrow + ks * 32 + q * 8);
        s16x8 a = __builtin_bit_cast(s16x8, au);
        s16x8 b0 = __builtin_bit_cast(s16x8, W2f4[(ks * 2 + 0) * 64 + lane]);
        s16x8 b1 = __builtin_bit_cast(s16x8, W2f4[(ks * 2 + 1) * 64 + lane]);
        acc0 = __builtin_amdgcn_mfma_f32_16x16x32_bf16(a, b0, acc0, 0, 0, 0);
        acc1 = __builtin_amdgcn_mfma_f32_16x16x32_bf16(a, b1, acc1, 0, 0, 0);
    }
    int cl = lane & 15, qr = lane >> 4;
#pragma unroll
    for (int j = 0; j < 4; ++j) {
        int n = n0 + qr * 4 + j;
        if (n < N) {
            h2[(size_t)n * 17 + cl] = acc0[j];
            if (cl == 0) h2[(size_t)n * 17 + 16] = acc1[j];
            if (cl == 1) asrc[n] = acc1[j];
            if (cl == 2) adst[n] = acc1[j];
        }
    }
}

// ===== fused layer2 softmax + aggregate + bias + log_softmax =====
// pass B: 4 edges in flight
__global__ __launch_bounds__(256) void k_out(
    const int* __restrict__ rs, const int* __restrict__ csr_src,
    const float* __restrict__ asrc, const float* __restrict__ adst,
    const float* __restrict__ h2,
    const float* __restrict__ b2, float* __restrict__ out, int N)
{
    int node = blockIdx.x * 4 + (threadIdx.x >> 6);
    if (node >= N) return;
    int lane = threadIdx.x & 63;
    int base = rs[node], deg = rs[node + 1] - base;
    float ad = adst[node];

    float m = -1e30f, s = 0.f;
    for (int j = lane; j < deg; j += 64) {
        float el = asrc[csr_src[base + j]] + ad;
        el = el >= 0.f ? el : NEG_SLOPE * el;
        if (el > m) { s = s * __expf(m - el) + 1.f; m = el; }
        else        { s += __expf(el - m); }
    }
#pragma unroll
    for (int off = 1; off < 64; off <<= 1) {
        float m2 = __shfl_xor(m, off, 64);
        float s2 = __shfl_xor(s, off, 64);
        float M = fmaxf(m, m2);
        s = s * __expf(m - M) + s2 * __expf(m2 - M);
        m = M;
    }
    float inv = 1.f / (s + 1e-16f);

    int c = lane & 31, jsub = lane >> 5;
    int end = base + deg;
    float acc = 0.f;
    if (c < 17) {
        int p = base + jsub;
        for (; p + 6 < end; p += 8) {
            int src0 = csr_src[p];
            int src1 = csr_src[p + 2];
            int src2 = csr_src[p + 4];
            int src3 = csr_src[p + 6];
            float e0 = asrc[src0] + ad;
            float e1 = asrc[src1] + ad;
            float e2 = asrc[src2] + ad;
            float e3 = asrc[src3] + ad;
            float h0 = h2[(size_t)src0 * 17 + c];
            float h1 = h2[(size_t)src1 * 17 + c];
            float h0b = h2[(size_t)src2 * 17 + c];
            float h1b = h2[(size_t)src3 * 17 + c];
            e0 = e0 >= 0.f ? e0 : NEG_SLOPE * e0;
            e1 = e1 >= 0.f ? e1 : NEG_SLOPE * e1;
            e2 = e2 >= 0.f ? e2 : NEG_SLOPE * e2;
            e3 = e3 >= 0.f ? e3 : NEG_SLOPE * e3;
            acc += __expf(e0 - m) * inv * h0 + __expf(e1 - m) * inv * h1
                 + __expf(e2 - m) * inv * h0b + __expf(e3 - m) * inv * h1b;
        }
        for (; p < end; p += 2) {
            int src = csr_src[p];
            float el = asrc[src] + ad;
            el = el >= 0.f ? el : NEG_SLOPE * el;
            acc += __expf(el - m) * inv * h2[(size_t)src * 17 + c];
        }
    }
    acc += __shfl_xor(acc, 32, 64);
    float logit = (c < 17) ? acc + b2[c] : -1e30f;
    float mm = logit;
#pragma unroll
    for (int off = 1; off < 32; off <<= 1) mm = fmaxf(mm, __shfl_xor(mm, off, 32));
    float p = (c < 17) ? __expf(logit - mm) : 0.f;
    float ssum = p;
#pragma unroll
    for (int off = 1; off < 32; off <<= 1) ssum += __shfl_xor(ssum, off, 32);
    if (c < 17 && jsub == 0) out[(size_t)node * 17 + c] = logit - mm - logf(ssum);
}

extern "C" void kernel_launch(void* const* d_in, const int* in_sizes, int n_in,
                              void* d_out, int out_size, void* d_ws, size_t ws_size,
                              hipStream_t stream)
{
    const float* x      = (const float*)d_in[0];
    const int*   ei     = (const int*)d_in[1];
    const float* W1     = (const float*)d_in[2];
    const float* asrc1w = (const float*)d_in[3];
    const float* adst1w = (const float*)d_in[4];
    const float* b1     = (const float*)d_in[5];
    const float* W2     = (const float*)d_in[6];
    const float* asrc2w = (const float*)d_in[7];
    const float* adst2w = (const float*)d_in[8];
    const float* b2     = (const float*)d_in[9];
    float* out = (float*)d_out;

    const int N = in_sizes[0] / 64;
    const int E = in_sizes[1] / 2;
    const int Etot = N + E;
    const int NB = (N + 1023) / 1024;

    // workspace layout
    float* ws = (float*)d_ws;
    size_t o = 0;
    bf16*  y      = (bf16*)(ws + o); o += (size_t)N * 256;   // N*512 bf16
    float* wboth  = ws + o; o += 1024;
    unsigned short* W1f = (unsigned short*)(ws + o); o += 64 * 512 / 2;  // 32768 halves
    unsigned short* W2f = (unsigned short*)(ws + o); o += 32 * 512 / 2;  // 16384 bf16
    float* asrc1  = ws + o; o += (size_t)N * 8;
    float* adst1  = ws + o; o += (size_t)N * 8;
    unsigned short* aEb = (unsigned short*)(ws + o); o += (size_t)Etot * 4;  // Etot*8 bf16
    float* h2     = ws + o; o += (size_t)N * 17;
    float* asrc2  = ws + o; o += (size_t)N;
    float* adst2  = ws + o; o += (size_t)N;
    int* deg      = (int*)(ws + o); o += (size_t)N;
    int* cur      = (int*)(ws + o); o += (size_t)N;
    int* rs       = (int*)(ws + o); o += (size_t)N + 1;
    int* bsum     = (int*)(ws + o); o += 1024;
    int* csr_src  = (int*)(ws + o); o += (size_t)Etot;

    // deg and cur are adjacent: one memset covers both
    hipMemsetAsync(deg, 0, (size_t)N * 2 * 4, stream);

    // CSR build (hierarchical scan)
    {
        int blk = 256, g = (Etot + blk - 1) / blk;
        k_hist<<<g, blk, 0, stream>>>(ei, E, Etot, deg);
        k_scan1<<<NB, 1024, 0, stream>>>(deg, rs, bsum, N);
        k_scan2<<<1, 1024, 0, stream>>>(bsum, rs, NB, N);
        k_scan3<<<(N + 255) / 256, 256, 0, stream>>>(rs, bsum, N);
        k_fill<<<g, blk, 0, stream>>>(ei, E, Etot, rs, cur, csr_src);
    }

    // merged setup (wboth + W1f + W2f)
    k_setup<<<97, 512, 0, stream>>>(W1, asrc1w, adst1w, W2, asrc2w, adst2w,
                                    wboth, W1f, W2f);

    // layer 1
    k_alpha1n<<<(N + 15) / 16, 256, 0, stream>>>(x, wboth, asrc1, adst1, N);
    k_sm1<<<(N + 3) / 4, 256, 0, stream>>>(rs, csr_src, asrc1, adst1, aEb, N);
    k_agg_gemm1<<<(N + NPB - 1) / NPB, 512, 0, stream>>>(
        rs, csr_src, aEb, x, W1f, b1, y, N);

    // layer 2
    k_gemm2<<<(N + 127) / 128, 512, 0, stream>>>(y, W2f, h2, asrc2, adst2, N);
    k_out<<<(N + 3) / 4, 256, 0, stream>>>(rs, csr_src, asrc2, adst2, h2, b2, out, N);
}